// Round 1
// baseline (1187.732 us; speedup 1.0000x reference)
//
#include <hip/hip_runtime.h>

#define B_ 16
#define S_ 512
#define T_ 2048
#define D_ 256
#define H_ 128

// ---------------- workspace layout (floats) ----------------
#define WS_C     0          // c centers [B,S] : 8192
#define WS_W2    8192       // w2 [B,T] : 32768
#define WS_WHHT  40960      // WhhT [2][2][128][512] : 262144
#define WS_XG    303104     // Xg [2][S][B][512] : 8388608
#define WS_H1    8691712    // H [B][S][256] : 2097152
// total 10788864 floats = 43.2 MB

// ---------------- output layout (floats) ----------------
#define OUT_MAIN   0          // [B,T,D]  8388608
#define OUT_LOGDUR 8388608    // [B,S]    8192
#define OUT_DUR    8396800    // [B,S]    8192
#define OUT_W      8404992    // [B,S,T]  16777216

// ============ prep: cumsum -> centers, copy duration ============
__global__ void prep_kernel(const float* __restrict__ dur, float* __restrict__ c,
                            float* __restrict__ out_dur) {
    int b = blockIdx.x;
    int s = threadIdx.x;
    __shared__ float sc[S_];
    float d = dur[b * S_ + s];
    sc[s] = d;
    __syncthreads();
    float v = d;
    for (int off = 1; off < S_; off <<= 1) {
        float add = (s >= off) ? sc[s - off] : 0.f;
        __syncthreads();
        v += add;
        sc[s] = v;
        __syncthreads();
    }
    c[b * S_ + s] = v - 0.5f * d;
    out_dur[b * S_ + s] = d;
}

// ============ transpose Whh -> WhhT[l][d][k][j] ============
__global__ void twhh_kernel(const float* __restrict__ Whh0, const float* __restrict__ Whh1,
                            float* __restrict__ WhhT) {
    int e = blockIdx.x * 256 + threadIdx.x;  // 2*2*512*128 = 262144
    if (e >= 262144) return;
    int l = e >> 17;
    int r = e & 131071;
    int d = r >> 16;
    int rr = r & 65535;
    int j = rr >> 7;
    int k = rr & 127;
    const float* W = l ? Whh1 : Whh0;
    WhhT[l * 131072 + d * 65536 + k * 512 + j] = W[d * 65536 + j * 128 + k];
}

// ============ gemm: Xg[dir][s][b][jj] = A[m,:256] . Wih[n,:256] + bias[n] ============
// A [8192,256] rowmajor (m = b*512+s), Wih [1024,256] rowmajor (n = dir*512+jj)
#define BM 64
#define BN 64
#define BK 64
__global__ __launch_bounds__(256) void gemm_xg_kernel(const float* __restrict__ A,
                                                      const float* __restrict__ Bw,
                                                      const float* __restrict__ bias,
                                                      float* __restrict__ Xg) {
    __shared__ float As[BK][BM + 4];
    __shared__ float Bs[BK][BN + 4];
    int tid = threadIdx.x;
    int m0 = blockIdx.x * BM;
    int n0 = blockIdx.y * BN;
    int tm = tid >> 4, tn = tid & 15;
    float acc[4][4] = {};
    for (int k0 = 0; k0 < 256; k0 += BK) {
#pragma unroll
        for (int i = 0; i < 4; i++) {
            int p = tid + 256 * i;
            int m = p >> 4, kq = p & 15;
            float4 av = *reinterpret_cast<const float4*>(&A[(size_t)(m0 + m) * 256 + k0 + 4 * kq]);
            As[4 * kq + 0][m] = av.x; As[4 * kq + 1][m] = av.y;
            As[4 * kq + 2][m] = av.z; As[4 * kq + 3][m] = av.w;
            float4 bv = *reinterpret_cast<const float4*>(&Bw[(size_t)(n0 + m) * 256 + k0 + 4 * kq]);
            Bs[4 * kq + 0][m] = bv.x; Bs[4 * kq + 1][m] = bv.y;
            Bs[4 * kq + 2][m] = bv.z; Bs[4 * kq + 3][m] = bv.w;
        }
        __syncthreads();
#pragma unroll
        for (int k = 0; k < BK; k++) {
            float4 a4 = *reinterpret_cast<const float4*>(&As[k][4 * tm]);
            float4 b4 = *reinterpret_cast<const float4*>(&Bs[k][4 * tn]);
            float av[4] = {a4.x, a4.y, a4.z, a4.w};
            float bv[4] = {b4.x, b4.y, b4.z, b4.w};
#pragma unroll
            for (int i = 0; i < 4; i++)
#pragma unroll
                for (int j = 0; j < 4; j++) acc[i][j] += av[i] * bv[j];
        }
        __syncthreads();
    }
#pragma unroll
    for (int i = 0; i < 4; i++) {
        int m = m0 + 4 * tm + i;
        int b = m >> 9, s = m & 511;
        int n = n0 + 4 * tn;
        int dir = n >> 9, jj = n & 511;
        float4 o;
        o.x = acc[i][0] + bias[n + 0];
        o.y = acc[i][1] + bias[n + 1];
        o.z = acc[i][2] + bias[n + 2];
        o.w = acc[i][3] + bias[n + 3];
        *reinterpret_cast<float4*>(&Xg[((size_t)(dir * 512 + s) * 16 + b) * 512 + jj]) = o;
    }
}

// ============ LSTM scan: one block per (dir, batch) ============
__global__ __launch_bounds__(512) void lstm_scan_kernel(const float* __restrict__ Xg,
                                                        const float* __restrict__ WhhT,
                                                        float* __restrict__ Hout) {
    int dir = blockIdx.x >> 4;
    int b = blockIdx.x & 15;
    int j = threadIdx.x;  // gate row 0..511
    float w[128];
    const float* wt = WhhT + dir * 65536 + j;
#pragma unroll
    for (int k = 0; k < 128; k++) w[k] = wt[k * 512];
    __shared__ __align__(16) float h_s[128];
    __shared__ float act[512];
    float c = 0.f;
    if (j < 128) h_s[j] = 0.f;
    __syncthreads();
    const float* xg_base = Xg + (size_t)dir * (512 * 16 * 512) + b * 512;
    int s0 = (dir == 0) ? 0 : 511;
    float xg = xg_base[(size_t)s0 * 8192 + j];
    for (int t = 0; t < 512; t++) {
        int s_next = (dir == 0) ? (t < 511 ? t + 1 : 511) : (t < 511 ? 510 - t : 0);
        float xg_next = xg_base[(size_t)s_next * 8192 + j];
        float a0 = 0.f, a1 = 0.f, a2 = 0.f, a3 = 0.f;
        const float4* h4 = reinterpret_cast<const float4*>(h_s);
#pragma unroll
        for (int k = 0; k < 32; k++) {
            float4 hv = h4[k];
            a0 += hv.x * w[4 * k + 0];
            a1 += hv.y * w[4 * k + 1];
            a2 += hv.z * w[4 * k + 2];
            a3 += hv.w * w[4 * k + 3];
        }
        float g = xg + ((a0 + a1) + (a2 + a3));
        int grp = j >> 7;
        float a;
        if (grp == 2) {
            float xc = fminf(fmaxf(g, -15.f), 15.f);
            float e = __expf(-2.f * xc);
            a = (1.f - e) / (1.f + e);
        } else {
            a = 1.f / (1.f + __expf(-g));
        }
        act[j] = a;
        __syncthreads();
        if (j < 128) {
            float i_ = act[j], f_ = act[128 + j], gg = act[256 + j], o_ = act[384 + j];
            c = f_ * c + i_ * gg;
            float xc = fminf(fmaxf(c, -15.f), 15.f);
            float e = __expf(-2.f * xc);
            float th = (1.f - e) / (1.f + e);
            float h = o_ * th;
            h_s[j] = h;
            int s_cur = (dir == 0) ? t : 511 - t;
            Hout[((size_t)b * 512 + s_cur) * 256 + dir * 128 + j] = h;
        }
        __syncthreads();
        xg = xg_next;
    }
}

// ============ projection: log_dur ============
__global__ void proj_kernel(const float* __restrict__ H2, const float* __restrict__ pw,
                            const float* __restrict__ pb, const unsigned char* __restrict__ mask,
                            float* __restrict__ out) {
    int row = blockIdx.x * 4 + (threadIdx.x >> 6);
    int lane = threadIdx.x & 63;
    float4 h = *reinterpret_cast<const float4*>(&H2[(size_t)row * 256 + lane * 4]);
    float4 w = *reinterpret_cast<const float4*>(&pw[lane * 4]);
    float v = h.x * w.x + h.y * w.y + h.z * w.z + h.w * w.w;
#pragma unroll
    for (int off = 32; off; off >>= 1) v += __shfl_xor(v, off);
    if (lane == 0) {
        float r = v + pb[0];
        r = r > 0.f ? r : 0.f;
        if (mask[row]) r = 0.f;
        out[row] = r;
    }
}

// ============ w2[b,t] = sum_s exp(-0.1 (t+1-c)^2) ============
__global__ void wsum_kernel(const float* __restrict__ c, float* __restrict__ w2) {
    int idx = blockIdx.x * 4 + (threadIdx.x >> 6);  // b*2048+t
    int lane = threadIdx.x & 63;
    int b = idx >> 11, t = idx & 2047;
    float tv = (float)(t + 1);
    const float* cb = c + b * 512;
    float sum = 0.f;
#pragma unroll
    for (int i = 0; i < 8; i++) {
        float d = tv - cb[lane + 64 * i];
        sum += __expf(-0.1f * d * d);
    }
#pragma unroll
    for (int off = 32; off; off >>= 1) sum += __shfl_xor(sum, off);
    if (lane == 0) w2[idx] = (sum == 0.f) ? 1.f : sum;
}

// ============ w[b,s,t] = exp(...)/w2 ============
__global__ void wwrite_kernel(const float* __restrict__ c, const float* __restrict__ w2,
                              float* __restrict__ w) {
    int gid = blockIdx.x * 256 + threadIdx.x;  // B*S*T = 16,777,216
    int t = gid & 2047;
    int bs = gid >> 11;
    int b = bs >> 9;
    float cv = c[bs];
    float tv = (float)(t + 1);
    float d = tv - cv;
    float e = __expf(-0.1f * d * d);
    w[gid] = e / w2[b * 2048 + t];
}

// ============ einsum: out[b,t,d] = sum_s w[b,s,t]*x[b,s,d] ============
__global__ __launch_bounds__(256) void gemm_out_kernel(const float* __restrict__ w,
                                                       const float* __restrict__ x,
                                                       float* __restrict__ out) {
    __shared__ float As[BK][BM + 4];  // [k=s][m=t]
    __shared__ float Bs[BK][BN + 4];  // [k=s][n=d]
    int b = blockIdx.z;
    int m0 = blockIdx.x * BM;  // t
    int n0 = blockIdx.y * BN;  // d
    const float* wb = w + (size_t)b * S_ * T_;
    const float* xb = x + (size_t)b * S_ * D_;
    int tid = threadIdx.x;
    int tm = tid >> 4, tn = tid & 15;
    float acc[4][4] = {};
    for (int k0 = 0; k0 < 512; k0 += BK) {
#pragma unroll
        for (int i = 0; i < 4; i++) {
            int p = tid + 256 * i;
            int kk = p >> 4, mq = p & 15;
            *reinterpret_cast<float4*>(&As[kk][4 * mq]) =
                *reinterpret_cast<const float4*>(&wb[(size_t)(k0 + kk) * T_ + m0 + 4 * mq]);
        }
#pragma unroll
        for (int i = 0; i < 4; i++) {
            int p = tid + 256 * i;
            int kk = p >> 4, nq = p & 15;
            *reinterpret_cast<float4*>(&Bs[kk][4 * nq]) =
                *reinterpret_cast<const float4*>(&xb[(size_t)(k0 + kk) * D_ + n0 + 4 * nq]);
        }
        __syncthreads();
#pragma unroll
        for (int k = 0; k < BK; k++) {
            float4 a4 = *reinterpret_cast<const float4*>(&As[k][4 * tm]);
            float4 b4 = *reinterpret_cast<const float4*>(&Bs[k][4 * tn]);
            float av[4] = {a4.x, a4.y, a4.z, a4.w};
            float bv[4] = {b4.x, b4.y, b4.z, b4.w};
#pragma unroll
            for (int i = 0; i < 4; i++)
#pragma unroll
                for (int j = 0; j < 4; j++) acc[i][j] += av[i] * bv[j];
        }
        __syncthreads();
    }
#pragma unroll
    for (int i = 0; i < 4; i++) {
        int m = m0 + 4 * tm + i;
        float4 o = {acc[i][0], acc[i][1], acc[i][2], acc[i][3]};
        *reinterpret_cast<float4*>(&out[((size_t)b * T_ + m) * D_ + n0 + 4 * tn]) = o;
    }
}

extern "C" void kernel_launch(void* const* d_in, const int* in_sizes, int n_in,
                              void* d_out, int out_size, void* d_ws, size_t ws_size,
                              hipStream_t stream) {
    const float* x = (const float*)d_in[0];
    const unsigned char* mask = (const unsigned char*)d_in[1];
    const float* dur = (const float*)d_in[2];
    const float* Wih0 = (const float*)d_in[3];
    const float* Whh0 = (const float*)d_in[4];
    const float* b0 = (const float*)d_in[5];
    const float* Wih1 = (const float*)d_in[6];
    const float* Whh1 = (const float*)d_in[7];
    const float* b1 = (const float*)d_in[8];
    const float* pw = (const float*)d_in[9];
    const float* pb = (const float*)d_in[10];

    float* out = (float*)d_out;
    float* ws = (float*)d_ws;
    float* c = ws + WS_C;
    float* w2 = ws + WS_W2;
    float* WhhT = ws + WS_WHHT;
    float* Xg = ws + WS_XG;
    float* H1 = ws + WS_H1;

    float* out_main = out + OUT_MAIN;
    float* out_logdur = out + OUT_LOGDUR;
    float* out_dur = out + OUT_DUR;
    float* out_w = out + OUT_W;

    // ---- prep: centers + duration copy ----
    prep_kernel<<<16, 512, 0, stream>>>(dur, c, out_dur);
    twhh_kernel<<<1024, 256, 0, stream>>>(Whh0, Whh1, WhhT);

    // ---- gaussian upsampling path ----
    wsum_kernel<<<8192, 256, 0, stream>>>(c, w2);
    wwrite_kernel<<<65536, 256, 0, stream>>>(c, w2, out_w);
    gemm_out_kernel<<<dim3(32, 4, 16), 256, 0, stream>>>(out_w, x, out_main);

    // ---- BiLSTM layer 0 ----
    gemm_xg_kernel<<<dim3(128, 16), 256, 0, stream>>>(x, Wih0, b0, Xg);
    lstm_scan_kernel<<<32, 512, 0, stream>>>(Xg, WhhT, H1);

    // ---- BiLSTM layer 1 (reuse Xg, overwrite H1 after Xg gemm) ----
    gemm_xg_kernel<<<dim3(128, 16), 256, 0, stream>>>(H1, Wih1, b1, Xg);
    lstm_scan_kernel<<<32, 512, 0, stream>>>(Xg, WhhT + 131072, H1);

    // ---- projection ----
    proj_kernel<<<2048, 256, 0, stream>>>(H1, pw, pb, mask, out_logdur);
}